// Round 1
// baseline (385.689 us; speedup 1.0000x reference)
//
#include <hip/hip_runtime.h>
#include <hip/hip_bf16.h>
#include <math.h>

#define BB   8
#define LL   200
#define MM   4
#define SS   100
#define DD   128
#define FF   4
#define NT   300
#define ROWS (BB*LL)   // 1600

__device__ __forceinline__ float sigf(float x){ return 1.f/(1.f+expf(-x)); }

// ---------------------------------------------------------------------------
// Transpose the 4 LSTM weight matrices [512,128] -> [128,512] for coalesced
// reads in the gate GEMM / recurrence kernels.
__global__ void __launch_bounds__(256) k_transpose(
    const float* __restrict__ a0, const float* __restrict__ a1,
    const float* __restrict__ a2, const float* __restrict__ a3,
    float* __restrict__ o0, float* __restrict__ o1,
    float* __restrict__ o2, float* __restrict__ o3)
{
    int bid = blockIdx.x;
    int mat = bid >> 8;                       // 256 blocks per matrix
    int o   = ((bid & 255) << 8) + threadIdx.x;   // 0..65535 = k*512+g
    const float* src = (mat==0)?a0:(mat==1)?a1:(mat==2)?a2:a3;
    float*       dst = (mat==0)?o0:(mat==1)?o1:(mat==2)?o2:o3;
    int k = o >> 9;       // 0..127
    int g = o & 511;      // 0..511
    dst[o] = src[g*128 + k];
}

// ---------------------------------------------------------------------------
// Precompute T[s][j][t] = sum_d Wc[j,d]*Es[s,d]*Wp[s*428+d, t]  +  Wp[s*428+128+j, t]
// so each forget contribution is a 12-row gather of T.
__global__ void __launch_bounds__(256) k_tprep(
    const float* __restrict__ Es, const float* __restrict__ Wc,
    const float* __restrict__ Wp, float* __restrict__ T)
{
    int s  = blockIdx.x;      // 0..99
    int jc = blockIdx.y;      // 0..2  (chunk of 100 j)
    __shared__ float Bl[128][128];            // Bl[d][t] = Es[s,d]*Wp[s*428+d, t]
    int tid = threadIdx.x;
    const float* wp = Wp + (size_t)s*428*128;
    const float* es = Es + s*128;
    for (int idx = tid; idx < 128*128; idx += 256)
        Bl[idx>>7][idx&127] = es[idx>>7] * wp[idx];
    __syncthreads();

    int t  = tid & 127;
    int jh = tid >> 7;                        // two j-halves per chunk
    int jbase = jc*100 + jh*50;
    for (int pass = 0; pass < 5; pass++) {
        int j0 = jbase + pass*10;
        float acc[10];
        #pragma unroll
        for (int u = 0; u < 10; u++) acc[u] = 0.f;
        #pragma unroll 4
        for (int d = 0; d < 128; d++) {
            float b = Bl[d][t];
            #pragma unroll
            for (int u = 0; u < 10; u++)
                acc[u] += Wc[(j0+u)*128 + d] * b;   // uniform -> scalar loads
        }
        #pragma unroll
        for (int u = 0; u < 10; u++) {
            int j = j0 + u;
            T[((size_t)s*NT + j)*128 + t] = acc[u] + wp[(128 + j)*128 + t];
        }
    }
}

// ---------------------------------------------------------------------------
// Attention: att[row,:] = sum_{active m} softmax-weight_m * E_skill[c_m,:]
// softmax over all S=100 scores (inactive rows score 0).
__global__ void __launch_bounds__(128) k_attn(
    const int* __restrict__ q,  const int* __restrict__ c,
    const int* __restrict__ sq, const int* __restrict__ sc,
    const float* __restrict__ Eq, const float* __restrict__ Es,
    float* __restrict__ att0, float* __restrict__ att1)
{
    int row   = blockIdx.x;
    int which = blockIdx.y;
    const int* qq = which ? sq : q;
    const int* cc = which ? sc : c;
    float* out = which ? att1 : att0;
    int t = threadIdx.x;

    float eq = Eq[(size_t)qq[row]*128 + t];
    __shared__ float red[4][128];
    int   s[4];
    float es[4];
    #pragma unroll
    for (int m = 0; m < 4; m++) {
        s[m]  = cc[row*4 + m];
        es[m] = (s[m] >= 0) ? Es[s[m]*128 + t] : 0.f;
        red[m][t] = eq * es[m];
    }
    __syncthreads();
    for (int off = 64; off > 0; off >>= 1) {
        if (t < off) {
            #pragma unroll
            for (int m = 0; m < 4; m++) red[m][t] += red[m][t+off];
        }
        __syncthreads();
    }
    const float inv = 0.08838834764831845f;   // 1/sqrt(128)
    float dots[4];
    int   nact = 0;
    float mx = 0.f;                           // scores include >=96 zeros
    #pragma unroll
    for (int m = 0; m < 4; m++) {
        dots[m] = red[m][0] * inv;
        if (s[m] >= 0) { nact++; mx = fmaxf(mx, dots[m]); }
    }
    float Z = (float)(SS - nact) * expf(-mx);
    float w[4];
    #pragma unroll
    for (int m = 0; m < 4; m++) {
        w[m] = (s[m] >= 0) ? expf(dots[m] - mx) : 0.f;
        Z += w[m];
    }
    float a = 0.f;
    #pragma unroll
    for (int m = 0; m < 4; m++) a += (w[m]/Z) * es[m];
    out[row*128 + t] = a;
}

// ---------------------------------------------------------------------------
// xemb = [emb_q | emb_r | att] @ W_l2 + b_l2   (384 -> 128)
// shiftx = [emb_sq | s_att] @ W_l3 + b_l3      (256 -> 128)
// 8 rows per block to amortize weight reads.
__global__ void __launch_bounds__(128) k_proj(
    const int* __restrict__ q, const int* __restrict__ r, const int* __restrict__ sq,
    const float* __restrict__ Eq, const float* __restrict__ Er,
    const float* __restrict__ att, const float* __restrict__ satt,
    const float* __restrict__ Wl2, const float* __restrict__ bl2,
    const float* __restrict__ Wl3, const float* __restrict__ bl3,
    float* __restrict__ xemb, float* __restrict__ shiftx)
{
    int r0 = blockIdx.x * 8;
    int t  = threadIdx.x;
    __shared__ float x1[8][384];
    __shared__ float x2[8][256];
    #pragma unroll
    for (int i = 0; i < 8; i++) {
        int row = r0 + i;
        x1[i][t]       = Eq[(size_t)q[row]*128 + t];
        x1[i][128+t]   = Er[r[row]*128 + t];
        x1[i][256+t]   = att[row*128 + t];
        x2[i][t]       = Eq[(size_t)sq[row]*128 + t];
        x2[i][128+t]   = satt[row*128 + t];
    }
    __syncthreads();
    float acc[8];
    #pragma unroll
    for (int i = 0; i < 8; i++) acc[i] = bl2[t];
    for (int k = 0; k < 384; k++) {
        float w = Wl2[k*128 + t];
        #pragma unroll
        for (int i = 0; i < 8; i++) acc[i] += x1[i][k] * w;
    }
    #pragma unroll
    for (int i = 0; i < 8; i++) xemb[(r0+i)*128 + t] = acc[i];

    #pragma unroll
    for (int i = 0; i < 8; i++) acc[i] = bl3[t];
    for (int k = 0; k < 256; k++) {
        float w = Wl3[k*128 + t];
        #pragma unroll
        for (int i = 0; i < 8; i++) acc[i] += x2[i][k] * w;
    }
    #pragma unroll
    for (int i = 0; i < 8; i++) shiftx[(r0+i)*128 + t] = acc[i];
}

// ---------------------------------------------------------------------------
// fh[row,:] = b_pre + sum over active m, f of
//             T[s][f*25+rg] + T[s][100+f*25+pc_f] + T[s][200+f*25+ac_f]
__global__ void __launch_bounds__(128) k_fh(
    const int* __restrict__ c,  const int* __restrict__ rg,
    const int* __restrict__ pc, const int* __restrict__ ac,
    const int* __restrict__ c2, const int* __restrict__ rg2,
    const int* __restrict__ pc2,const int* __restrict__ ac2,
    const float* __restrict__ T, const float* __restrict__ bpre,
    float* __restrict__ fh0, float* __restrict__ fh1)
{
    int row   = blockIdx.x;
    int which = blockIdx.y;
    const int* C  = which ? c2  : c;
    const int* RG = which ? rg2 : rg;
    const int* PC = which ? pc2 : pc;
    const int* AC = which ? ac2 : ac;
    float* out = which ? fh1 : fh0;
    int t = threadIdx.x;

    float acc = bpre[t];
    for (int m = 0; m < 4; m++) {
        int s = C[row*4 + m];
        if (s < 0) continue;                  // block-uniform branch
        int rgv = RG[row*4 + m];
        const float* Ts = T + (size_t)s*NT*128;
        #pragma unroll
        for (int f = 0; f < 4; f++) {
            int j1 = f*25 + rgv;
            int j2 = 100 + f*25 + PC[(row*4+m)*4 + f];
            int j3 = 200 + f*25 + AC[(row*4+m)*4 + f];
            acc += Ts[j1*128 + t] + Ts[j2*128 + t] + Ts[j3*128 + t];
        }
    }
    out[row*128 + t] = acc;
}

// ---------------------------------------------------------------------------
// gates_x = X @ wih.T + (bih + bhh) : [1600,128] @ [128,512] for both LSTMs.
__global__ void __launch_bounds__(256) k_gates(
    const float* __restrict__ xemb, const float* __restrict__ fh,
    const float* __restrict__ wT_in, const float* __restrict__ wT_fg,
    const float* __restrict__ bih_in, const float* __restrict__ bhh_in,
    const float* __restrict__ bih_fg, const float* __restrict__ bhh_fg,
    float* __restrict__ g_in, float* __restrict__ g_fg)
{
    int which = blockIdx.y;
    const float* X  = which ? fh     : xemb;
    const float* Wt = which ? wT_fg  : wT_in;
    const float* b1 = which ? bih_fg : bih_in;
    const float* b2 = which ? bhh_fg : bhh_in;
    float* G = which ? g_fg : g_in;

    int r0  = blockIdx.x * 16;
    int tid = threadIdx.x;
    __shared__ float xl[16][128];
    for (int idx = tid; idx < 16*128; idx += 256)
        xl[idx>>7][idx&127] = X[(size_t)r0*128 + idx];
    __syncthreads();

    int g0 = tid, g1 = tid + 256;
    float a0[16], a1[16];
    #pragma unroll
    for (int i = 0; i < 16; i++) { a0[i] = 0.f; a1[i] = 0.f; }
    for (int k = 0; k < 128; k++) {
        float w0 = Wt[k*512 + g0];
        float w1 = Wt[k*512 + g1];
        #pragma unroll
        for (int i = 0; i < 16; i++) { a0[i] += xl[i][k]*w0; a1[i] += xl[i][k]*w1; }
    }
    float bb0 = b1[g0] + b2[g0];
    float bb1 = b1[g1] + b2[g1];
    #pragma unroll
    for (int i = 0; i < 16; i++) {
        G[(size_t)(r0+i)*512 + g0] = a0[i] + bb0;
        G[(size_t)(r0+i)*512 + g1] = a1[i] + bb1;
    }
}

// ---------------------------------------------------------------------------
// LSTM over 8 steps (axis 0 = B), batch = 200 independent rows.
// One block owns 4 rows and loops all steps; hs[t,row,:] -> out[(t*200+row)*128].
__global__ void __launch_bounds__(256) k_lstm(
    const float* __restrict__ g_in, const float* __restrict__ g_fg,
    const float* __restrict__ whhT_in, const float* __restrict__ whhT_fg,
    float* __restrict__ h_in_out, float* __restrict__ h_fg_out)
{
    int which = blockIdx.y;
    const float* GX = which ? g_fg    : g_in;
    const float* Wt = which ? whhT_fg : whhT_in;
    float* OUT = which ? h_fg_out : h_in_out;

    int row0 = blockIdx.x * 4;
    int tid  = threadIdx.x;
    __shared__ float h[4][128], cs[4][128], g[4][512];
    for (int idx = tid; idx < 512; idx += 256) {
        h[idx>>7][idx&127]  = 0.f;
        cs[idx>>7][idx&127] = 0.f;
    }
    __syncthreads();

    for (int t = 0; t < 8; t++) {
        int g0 = tid, g1 = tid + 256;
        float a[4][2];
        #pragma unroll
        for (int rr = 0; rr < 4; rr++) {
            a[rr][0] = GX[(size_t)(t*200 + row0 + rr)*512 + g0];
            a[rr][1] = GX[(size_t)(t*200 + row0 + rr)*512 + g1];
        }
        for (int k = 0; k < 128; k++) {
            float w0 = Wt[k*512 + g0];
            float w1 = Wt[k*512 + g1];
            #pragma unroll
            for (int rr = 0; rr < 4; rr++) {
                a[rr][0] += h[rr][k]*w0;
                a[rr][1] += h[rr][k]*w1;
            }
        }
        __syncthreads();                      // all h reads done
        #pragma unroll
        for (int rr = 0; rr < 4; rr++) { g[rr][g0] = a[rr][0]; g[rr][g1] = a[rr][1]; }
        __syncthreads();                      // gates visible
        for (int p = tid; p < 512; p += 256) {
            int rr = p >> 7, d = p & 127;
            float gi = g[rr][d], gf = g[rr][128+d], gg = g[rr][256+d], go = g[rr][384+d];
            float c_new = sigf(gf)*cs[rr][d] + sigf(gi)*tanhf(gg);
            float h_new = sigf(go)*tanhf(c_new);
            cs[rr][d] = c_new;
            h[rr][d]  = h_new;
            OUT[(size_t)(t*200 + row0 + rr)*128 + d] = h_new;
        }
        __syncthreads();                      // state updated before next step
    }
}

// ---------------------------------------------------------------------------
// x1 = relu([shiftx | input_h] @ W_fc4 + b4); x2 = relu([fh_shift | forget_h] @ W_fc5 + b5)
// y = sigmoid([x1|x2] @ W_fc3 + b3)
__global__ void __launch_bounds__(128) k_final(
    const float* __restrict__ shiftx, const float* __restrict__ h_in,
    const float* __restrict__ fh_shift, const float* __restrict__ h_fg,
    const float* __restrict__ Wfc4, const float* __restrict__ bfc4,
    const float* __restrict__ Wfc5, const float* __restrict__ bfc5,
    const float* __restrict__ Wfc3, const float* __restrict__ bfc3,
    float* __restrict__ out)
{
    int r0 = blockIdx.x * 8;
    int t  = threadIdx.x;
    __shared__ float xc1[8][256], xc2[8][256];
    #pragma unroll
    for (int i = 0; i < 8; i++) {
        xc1[i][t]     = shiftx[(r0+i)*128 + t];
        xc1[i][128+t] = h_in[(r0+i)*128 + t];
        xc2[i][t]     = fh_shift[(r0+i)*128 + t];
        xc2[i][128+t] = h_fg[(r0+i)*128 + t];
    }
    __syncthreads();
    float a1[8], a2[8];
    #pragma unroll
    for (int i = 0; i < 8; i++) { a1[i] = bfc4[t]; a2[i] = bfc5[t]; }
    for (int k = 0; k < 256; k++) {
        float w4 = Wfc4[k*128 + t];
        float w5 = Wfc5[k*128 + t];
        #pragma unroll
        for (int i = 0; i < 8; i++) { a1[i] += xc1[i][k]*w4; a2[i] += xc2[i][k]*w5; }
    }
    __shared__ float red[8][129];
    float w3a = Wfc3[t], w3b = Wfc3[128 + t];
    #pragma unroll
    for (int i = 0; i < 8; i++) {
        float x1v = fmaxf(a1[i], 0.f);
        float x2v = fmaxf(a2[i], 0.f);
        red[i][t] = x1v*w3a + x2v*w3b;
    }
    __syncthreads();
    for (int off = 64; off > 0; off >>= 1) {
        if (t < off) {
            #pragma unroll
            for (int i = 0; i < 8; i++) red[i][t] += red[i][t+off];
        }
        __syncthreads();
    }
    if (t < 8) out[r0 + t] = 1.f/(1.f + expf(-(red[t][0] + bfc3[0])));
}

// ---------------------------------------------------------------------------
extern "C" void kernel_launch(void* const* d_in, const int* in_sizes, int n_in,
                              void* d_out, int out_size, void* d_ws, size_t ws_size,
                              hipStream_t stream)
{
    const int*   q      = (const int*)d_in[0];
    const int*   c      = (const int*)d_in[1];
    const int*   sq     = (const int*)d_in[2];
    const int*   sc     = (const int*)d_in[3];
    const int*   r      = (const int*)d_in[4];
    const int*   rg     = (const int*)d_in[5];
    const int*   pc     = (const int*)d_in[6];
    const int*   ac     = (const int*)d_in[7];
    const int*   srg    = (const int*)d_in[8];
    const int*   spc    = (const int*)d_in[9];
    const int*   sac    = (const int*)d_in[10];
    const float* Es     = (const float*)d_in[11];
    const float* Eq     = (const float*)d_in[12];
    const float* Er     = (const float*)d_in[13];
    const float* wih_in = (const float*)d_in[14];
    const float* whh_in = (const float*)d_in[15];
    const float* bih_in = (const float*)d_in[16];
    const float* bhh_in = (const float*)d_in[17];
    const float* wih_fg = (const float*)d_in[18];
    const float* whh_fg = (const float*)d_in[19];
    const float* bih_fg = (const float*)d_in[20];
    const float* bhh_fg = (const float*)d_in[21];
    const float* Wl2    = (const float*)d_in[22];
    const float* bl2    = (const float*)d_in[23];
    const float* Wl3    = (const float*)d_in[24];
    const float* bl3    = (const float*)d_in[25];
    const float* Wfc3   = (const float*)d_in[26];
    const float* bfc3   = (const float*)d_in[27];
    const float* Wfc4   = (const float*)d_in[28];
    const float* bfc4   = (const float*)d_in[29];
    const float* Wfc5   = (const float*)d_in[30];
    const float* bfc5   = (const float*)d_in[31];
    const float* Wc     = (const float*)d_in[32];
    const float* Wp     = (const float*)d_in[33];
    const float* bpre   = (const float*)d_in[34];

    float* W = (float*)d_ws;
    float* T       = W;  W += 100*NT*128;    // 3,840,000
    float* att     = W;  W += ROWS*128;
    float* satt    = W;  W += ROWS*128;
    float* xemb    = W;  W += ROWS*128;
    float* shiftx  = W;  W += ROWS*128;
    float* fh0     = W;  W += ROWS*128;      // main forget (feeds LSTM)
    float* fh1     = W;  W += ROWS*128;      // shift forget (used raw in x2)
    float* wT_in   = W;  W += 512*128;
    float* whhT_in = W;  W += 512*128;
    float* wT_fg   = W;  W += 512*128;
    float* whhT_fg = W;  W += 512*128;
    float* g_in    = W;  W += ROWS*512;
    float* g_fg    = W;  W += ROWS*512;
    float* h_in    = W;  W += ROWS*128;
    float* h_fg    = W;  W += ROWS*128;

    hipLaunchKernelGGL(k_transpose, dim3(1024), dim3(256), 0, stream,
        wih_in, whh_in, wih_fg, whh_fg, wT_in, whhT_in, wT_fg, whhT_fg);
    hipLaunchKernelGGL(k_tprep, dim3(100, 3), dim3(256), 0, stream, Es, Wc, Wp, T);
    hipLaunchKernelGGL(k_attn, dim3(ROWS, 2), dim3(128), 0, stream,
        q, c, sq, sc, Eq, Es, att, satt);
    hipLaunchKernelGGL(k_proj, dim3(200), dim3(128), 0, stream,
        q, r, sq, Eq, Er, att, satt, Wl2, bl2, Wl3, bl3, xemb, shiftx);
    hipLaunchKernelGGL(k_fh, dim3(ROWS, 2), dim3(128), 0, stream,
        c, rg, pc, ac, sc, srg, spc, sac, T, bpre, fh0, fh1);
    hipLaunchKernelGGL(k_gates, dim3(100, 2), dim3(256), 0, stream,
        xemb, fh0, wT_in, wT_fg, bih_in, bhh_in, bih_fg, bhh_fg, g_in, g_fg);
    hipLaunchKernelGGL(k_lstm, dim3(50, 2), dim3(256), 0, stream,
        g_in, g_fg, whhT_in, whhT_fg, h_in, h_fg);
    hipLaunchKernelGGL(k_final, dim3(200), dim3(128), 0, stream,
        shiftx, h_in, fh1, h_fg, Wfc4, bfc4, Wfc5, bfc5, Wfc3, bfc3, (float*)d_out);
}

// Round 2
// 328.725 us; speedup vs baseline: 1.1733x; 1.1733x over previous
//
#include <hip/hip_runtime.h>
#include <hip/hip_bf16.h>
#include <math.h>

#define BB   8
#define LL   200
#define MM   4
#define SS   100
#define DD   128
#define FF   4
#define NT   300
#define ROWS (BB*LL)   // 1600
#define JT   32        // j-tile for k_tprep

__device__ __forceinline__ float sigf(float x){ return 1.f/(1.f+expf(-x)); }

// ---------------------------------------------------------------------------
// Weight prep:
//  mat0: wT_in  [128][512] = wih_in^T   (for k_gates)
//  mat1: wT_fg  [128][512] = wih_fg^T
//  mat2: whhP_in paired: out[(k*256+p)*2+c] = whh_in[(p+256c)*128+k]  (for k_lstm)
//  mat3: whhP_fg paired, same layout
__global__ void __launch_bounds__(256) k_transpose(
    const float* __restrict__ a0, const float* __restrict__ a1,
    const float* __restrict__ a2, const float* __restrict__ a3,
    float* __restrict__ o0, float* __restrict__ o1,
    float* __restrict__ o2, float* __restrict__ o3)
{
    int bid = blockIdx.x;
    int mat = bid >> 8;                           // 256 blocks per matrix
    int o   = ((bid & 255) << 8) + threadIdx.x;   // 0..65535
    if (mat < 2) {
        const float* src = mat ? a1 : a0;
        float*       dst = mat ? o1 : o0;
        int k = o >> 9, g = o & 511;
        dst[o] = src[g*128 + k];
    } else {
        const float* src = (mat==2) ? a2 : a3;
        float*       dst = (mat==2) ? o2 : o3;
        int k = o >> 9, rem = o & 511;
        int p = rem >> 1, c = rem & 1;
        dst[o] = src[(p + 256*c)*128 + k];
    }
}

// ---------------------------------------------------------------------------
// T[s][j][t] = sum_d Wc[j,d]*Es[s,d]*Wp[s*428+d, t]  +  Wp[s*428+128+j, t]
// Register-tiled: block = (s, j-chunk of 32). 256 thr = 64 t-pairs x 4 j-groups.
// Es is folded into the LDS-staged Wc chunk.
__global__ void __launch_bounds__(256) k_tprep(
    const float* __restrict__ Es, const float* __restrict__ Wc,
    const float* __restrict__ Wp, float* __restrict__ T)
{
    int s  = blockIdx.x;              // 0..99
    int jc = blockIdx.y;              // 0..9
    int j0 = jc * JT;                 // 0,32,...,288 (covers 300 w/ guard)
    __shared__ float WcL[JT][128];    // WcL[jj][d] = Wc[j0+jj, d] * Es[s, d]
    int tid = threadIdx.x;

    const float* es = Es + s*128;
    for (int idx = tid; idx < JT*128; idx += 256) {
        int jj = idx >> 7, d = idx & 127;
        int j = j0 + jj;
        WcL[jj][d] = (j < NT) ? Wc[j*128 + d] * es[d] : 0.f;
    }
    __syncthreads();

    const float*  wp  = Wp + (size_t)s*428*128;
    const float2* wp2 = (const float2*)wp;
    int tt = tid & 63;                // owns t = 2*tt, 2*tt+1
    int jg = tid >> 6;                // 0..3, owns 8 j's
    float2 acc[8];
    #pragma unroll
    for (int u = 0; u < 8; u++) acc[u] = make_float2(0.f, 0.f);

    #pragma unroll 4
    for (int d = 0; d < 128; d++) {
        float2 w = wp2[d*64 + tt];
        #pragma unroll
        for (int u = 0; u < 8; u++) {
            float wc = WcL[jg*8 + u][d];
            acc[u].x += wc * w.x;
            acc[u].y += wc * w.y;
        }
    }

    const float2* wpe = (const float2*)(wp + 128*128);   // rows 128..427
    float2* T2 = (float2*)T;
    #pragma unroll
    for (int u = 0; u < 8; u++) {
        int j = j0 + jg*8 + u;
        if (j < NT) {
            float2 b = wpe[(size_t)j*64 + tt];
            float2 o; o.x = acc[u].x + b.x; o.y = acc[u].y + b.y;
            T2[((size_t)s*NT + j)*64 + tt] = o;
        }
    }
}

// ---------------------------------------------------------------------------
// Attention: att[row,:] = sum_{active m} softmax-weight_m * E_skill[c_m,:]
__global__ void __launch_bounds__(128) k_attn(
    const int* __restrict__ q,  const int* __restrict__ c,
    const int* __restrict__ sq, const int* __restrict__ sc,
    const float* __restrict__ Eq, const float* __restrict__ Es,
    float* __restrict__ att0, float* __restrict__ att1)
{
    int row   = blockIdx.x;
    int which = blockIdx.y;
    const int* qq = which ? sq : q;
    const int* cc = which ? sc : c;
    float* out = which ? att1 : att0;
    int t = threadIdx.x;

    float eq = Eq[(size_t)qq[row]*128 + t];
    __shared__ float red[4][128];
    int   s[4];
    float es[4];
    #pragma unroll
    for (int m = 0; m < 4; m++) {
        s[m]  = cc[row*4 + m];
        es[m] = (s[m] >= 0) ? Es[s[m]*128 + t] : 0.f;
        red[m][t] = eq * es[m];
    }
    __syncthreads();
    for (int off = 64; off > 0; off >>= 1) {
        if (t < off) {
            #pragma unroll
            for (int m = 0; m < 4; m++) red[m][t] += red[m][t+off];
        }
        __syncthreads();
    }
    const float inv = 0.08838834764831845f;   // 1/sqrt(128)
    float dots[4];
    int   nact = 0;
    float mx = 0.f;                           // scores include >=96 zeros
    #pragma unroll
    for (int m = 0; m < 4; m++) {
        dots[m] = red[m][0] * inv;
        if (s[m] >= 0) { nact++; mx = fmaxf(mx, dots[m]); }
    }
    float Z = (float)(SS - nact) * expf(-mx);
    float w[4];
    #pragma unroll
    for (int m = 0; m < 4; m++) {
        w[m] = (s[m] >= 0) ? expf(dots[m] - mx) : 0.f;
        Z += w[m];
    }
    float a = 0.f;
    #pragma unroll
    for (int m = 0; m < 4; m++) a += (w[m]/Z) * es[m];
    out[row*128 + t] = a;
}

// ---------------------------------------------------------------------------
// xemb = [emb_q | emb_r | att] @ W_l2 + b_l2   (384 -> 128)
// shiftx = [emb_sq | s_att] @ W_l3 + b_l3      (256 -> 128)
__global__ void __launch_bounds__(128) k_proj(
    const int* __restrict__ q, const int* __restrict__ r, const int* __restrict__ sq,
    const float* __restrict__ Eq, const float* __restrict__ Er,
    const float* __restrict__ att, const float* __restrict__ satt,
    const float* __restrict__ Wl2, const float* __restrict__ bl2,
    const float* __restrict__ Wl3, const float* __restrict__ bl3,
    float* __restrict__ xemb, float* __restrict__ shiftx)
{
    int r0 = blockIdx.x * 8;
    int t  = threadIdx.x;
    __shared__ float x1[8][384];
    __shared__ float x2[8][256];
    #pragma unroll
    for (int i = 0; i < 8; i++) {
        int row = r0 + i;
        x1[i][t]       = Eq[(size_t)q[row]*128 + t];
        x1[i][128+t]   = Er[r[row]*128 + t];
        x1[i][256+t]   = att[row*128 + t];
        x2[i][t]       = Eq[(size_t)sq[row]*128 + t];
        x2[i][128+t]   = satt[row*128 + t];
    }
    __syncthreads();
    float acc[8];
    #pragma unroll
    for (int i = 0; i < 8; i++) acc[i] = bl2[t];
    for (int k = 0; k < 384; k++) {
        float w = Wl2[k*128 + t];
        #pragma unroll
        for (int i = 0; i < 8; i++) acc[i] += x1[i][k] * w;
    }
    #pragma unroll
    for (int i = 0; i < 8; i++) xemb[(r0+i)*128 + t] = acc[i];

    #pragma unroll
    for (int i = 0; i < 8; i++) acc[i] = bl3[t];
    for (int k = 0; k < 256; k++) {
        float w = Wl3[k*128 + t];
        #pragma unroll
        for (int i = 0; i < 8; i++) acc[i] += x2[i][k] * w;
    }
    #pragma unroll
    for (int i = 0; i < 8; i++) shiftx[(r0+i)*128 + t] = acc[i];
}

// ---------------------------------------------------------------------------
// fh[row,:] = b_pre + sum over active m, f of
//             T[s][f*25+rg] + T[s][100+f*25+pc_f] + T[s][200+f*25+ac_f]
__global__ void __launch_bounds__(128) k_fh(
    const int* __restrict__ c,  const int* __restrict__ rg,
    const int* __restrict__ pc, const int* __restrict__ ac,
    const int* __restrict__ c2, const int* __restrict__ rg2,
    const int* __restrict__ pc2,const int* __restrict__ ac2,
    const float* __restrict__ T, const float* __restrict__ bpre,
    float* __restrict__ fh0, float* __restrict__ fh1)
{
    int row   = blockIdx.x;
    int which = blockIdx.y;
    const int* C  = which ? c2  : c;
    const int* RG = which ? rg2 : rg;
    const int* PC = which ? pc2 : pc;
    const int* AC = which ? ac2 : ac;
    float* out = which ? fh1 : fh0;
    int t = threadIdx.x;

    float acc = bpre[t];
    for (int m = 0; m < 4; m++) {
        int s = C[row*4 + m];
        if (s < 0) continue;                  // block-uniform branch
        int rgv = RG[row*4 + m];
        const float* Ts = T + (size_t)s*NT*128;
        #pragma unroll
        for (int f = 0; f < 4; f++) {
            int j1 = f*25 + rgv;
            int j2 = 100 + f*25 + PC[(row*4+m)*4 + f];
            int j3 = 200 + f*25 + AC[(row*4+m)*4 + f];
            acc += Ts[j1*128 + t] + Ts[j2*128 + t] + Ts[j3*128 + t];
        }
    }
    out[row*128 + t] = acc;
}

// ---------------------------------------------------------------------------
// gates_x = X @ wih.T + (bih + bhh) : [1600,128] @ [128,512] for both LSTMs.
__global__ void __launch_bounds__(256) k_gates(
    const float* __restrict__ xemb, const float* __restrict__ fh,
    const float* __restrict__ wT_in, const float* __restrict__ wT_fg,
    const float* __restrict__ bih_in, const float* __restrict__ bhh_in,
    const float* __restrict__ bih_fg, const float* __restrict__ bhh_fg,
    float* __restrict__ g_in, float* __restrict__ g_fg)
{
    int which = blockIdx.y;
    const float* X  = which ? fh     : xemb;
    const float* Wt = which ? wT_fg  : wT_in;
    const float* b1 = which ? bih_fg : bih_in;
    const float* b2 = which ? bhh_fg : bhh_in;
    float* G = which ? g_fg : g_in;

    int r0  = blockIdx.x * 16;
    int tid = threadIdx.x;
    __shared__ float xl[16][128];
    for (int idx = tid; idx < 16*128; idx += 256)
        xl[idx>>7][idx&127] = X[(size_t)r0*128 + idx];
    __syncthreads();

    int g0 = tid, g1 = tid + 256;
    float a0[16], a1[16];
    #pragma unroll
    for (int i = 0; i < 16; i++) { a0[i] = 0.f; a1[i] = 0.f; }
    for (int k = 0; k < 128; k++) {
        float w0 = Wt[k*512 + g0];
        float w1 = Wt[k*512 + g1];
        #pragma unroll
        for (int i = 0; i < 16; i++) { a0[i] += xl[i][k]*w0; a1[i] += xl[i][k]*w1; }
    }
    float bb0 = b1[g0] + b2[g0];
    float bb1 = b1[g1] + b2[g1];
    #pragma unroll
    for (int i = 0; i < 16; i++) {
        G[(size_t)(r0+i)*512 + g0] = a0[i] + bb0;
        G[(size_t)(r0+i)*512 + g1] = a1[i] + bb1;
    }
}

// ---------------------------------------------------------------------------
// LSTM over 8 steps (axis 0 = B), batch = 200 independent rows.
// Block owns 4 rows, loops all steps. whh in paired layout: thread p's two
// gate columns (p, p+256) are one float2 load per k.
__global__ void __launch_bounds__(256) k_lstm(
    const float* __restrict__ g_in, const float* __restrict__ g_fg,
    const float* __restrict__ whhP_in, const float* __restrict__ whhP_fg,
    float* __restrict__ h_in_out, float* __restrict__ h_fg_out)
{
    int which = blockIdx.y;
    const float*  GX  = which ? g_fg : g_in;
    const float2* Wp2 = (const float2*)(which ? whhP_fg : whhP_in);
    float* OUT = which ? h_fg_out : h_in_out;

    int row0 = blockIdx.x * 4;
    int tid  = threadIdx.x;
    __shared__ float h[4][128], cs[4][128], g[4][512];
    for (int idx = tid; idx < 512; idx += 256) {
        h[idx>>7][idx&127]  = 0.f;
        cs[idx>>7][idx&127] = 0.f;
    }
    __syncthreads();

    for (int t = 0; t < 8; t++) {
        int p = tid;                          // gate cols p, p+256
        float a0[4], a1[4];
        #pragma unroll
        for (int rr = 0; rr < 4; rr++) {
            a0[rr] = GX[(size_t)(t*200 + row0 + rr)*512 + p];
            a1[rr] = GX[(size_t)(t*200 + row0 + rr)*512 + p + 256];
        }
        #pragma unroll 4
        for (int k = 0; k < 128; k++) {
            float2 w = Wp2[k*256 + p];
            #pragma unroll
            for (int rr = 0; rr < 4; rr++) {
                float hv = h[rr][k];
                a0[rr] += hv * w.x;
                a1[rr] += hv * w.y;
            }
        }
        __syncthreads();                      // all h reads done
        #pragma unroll
        for (int rr = 0; rr < 4; rr++) { g[rr][p] = a0[rr]; g[rr][p+256] = a1[rr]; }
        __syncthreads();                      // gates visible
        for (int q = tid; q < 512; q += 256) {
            int rr = q >> 7, d = q & 127;
            float gi = g[rr][d], gf = g[rr][128+d], gg = g[rr][256+d], go = g[rr][384+d];
            float c_new = sigf(gf)*cs[rr][d] + sigf(gi)*tanhf(gg);
            float h_new = sigf(go)*tanhf(c_new);
            cs[rr][d] = c_new;
            h[rr][d]  = h_new;
            OUT[(size_t)(t*200 + row0 + rr)*128 + d] = h_new;
        }
        __syncthreads();                      // state updated before next step
    }
}

// ---------------------------------------------------------------------------
// x1 = relu([shiftx | input_h] @ W_fc4 + b4); x2 = relu([fh_shift | forget_h] @ W_fc5 + b5)
// y = sigmoid([x1|x2] @ W_fc3 + b3)
__global__ void __launch_bounds__(128) k_final(
    const float* __restrict__ shiftx, const float* __restrict__ h_in,
    const float* __restrict__ fh_shift, const float* __restrict__ h_fg,
    const float* __restrict__ Wfc4, const float* __restrict__ bfc4,
    const float* __restrict__ Wfc5, const float* __restrict__ bfc5,
    const float* __restrict__ Wfc3, const float* __restrict__ bfc3,
    float* __restrict__ out)
{
    int r0 = blockIdx.x * 8;
    int t  = threadIdx.x;
    __shared__ float xc1[8][256], xc2[8][256];
    #pragma unroll
    for (int i = 0; i < 8; i++) {
        xc1[i][t]     = shiftx[(r0+i)*128 + t];
        xc1[i][128+t] = h_in[(r0+i)*128 + t];
        xc2[i][t]     = fh_shift[(r0+i)*128 + t];
        xc2[i][128+t] = h_fg[(r0+i)*128 + t];
    }
    __syncthreads();
    float a1[8], a2[8];
    #pragma unroll
    for (int i = 0; i < 8; i++) { a1[i] = bfc4[t]; a2[i] = bfc5[t]; }
    for (int k = 0; k < 256; k++) {
        float w4 = Wfc4[k*128 + t];
        float w5 = Wfc5[k*128 + t];
        #pragma unroll
        for (int i = 0; i < 8; i++) { a1[i] += xc1[i][k]*w4; a2[i] += xc2[i][k]*w5; }
    }
    __shared__ float red[8][129];
    float w3a = Wfc3[t], w3b = Wfc3[128 + t];
    #pragma unroll
    for (int i = 0; i < 8; i++) {
        float x1v = fmaxf(a1[i], 0.f);
        float x2v = fmaxf(a2[i], 0.f);
        red[i][t] = x1v*w3a + x2v*w3b;
    }
    __syncthreads();
    for (int off = 64; off > 0; off >>= 1) {
        if (t < off) {
            #pragma unroll
            for (int i = 0; i < 8; i++) red[i][t] += red[i][t+off];
        }
        __syncthreads();
    }
    if (t < 8) out[r0 + t] = 1.f/(1.f + expf(-(red[t][0] + bfc3[0])));
}

// ---------------------------------------------------------------------------
extern "C" void kernel_launch(void* const* d_in, const int* in_sizes, int n_in,
                              void* d_out, int out_size, void* d_ws, size_t ws_size,
                              hipStream_t stream)
{
    const int*   q      = (const int*)d_in[0];
    const int*   c      = (const int*)d_in[1];
    const int*   sq     = (const int*)d_in[2];
    const int*   sc     = (const int*)d_in[3];
    const int*   r      = (const int*)d_in[4];
    const int*   rg     = (const int*)d_in[5];
    const int*   pc     = (const int*)d_in[6];
    const int*   ac     = (const int*)d_in[7];
    const int*   srg    = (const int*)d_in[8];
    const int*   spc    = (const int*)d_in[9];
    const int*   sac    = (const int*)d_in[10];
    const float* Es     = (const float*)d_in[11];
    const float* Eq     = (const float*)d_in[12];
    const float* Er     = (const float*)d_in[13];
    const float* wih_in = (const float*)d_in[14];
    const float* whh_in = (const float*)d_in[15];
    const float* bih_in = (const float*)d_in[16];
    const float* bhh_in = (const float*)d_in[17];
    const float* wih_fg = (const float*)d_in[18];
    const float* whh_fg = (const float*)d_in[19];
    const float* bih_fg = (const float*)d_in[20];
    const float* bhh_fg = (const float*)d_in[21];
    const float* Wl2    = (const float*)d_in[22];
    const float* bl2    = (const float*)d_in[23];
    const float* Wl3    = (const float*)d_in[24];
    const float* bl3    = (const float*)d_in[25];
    const float* Wfc3   = (const float*)d_in[26];
    const float* bfc3   = (const float*)d_in[27];
    const float* Wfc4   = (const float*)d_in[28];
    const float* bfc4   = (const float*)d_in[29];
    const float* Wfc5   = (const float*)d_in[30];
    const float* bfc5   = (const float*)d_in[31];
    const float* Wc     = (const float*)d_in[32];
    const float* Wp     = (const float*)d_in[33];
    const float* bpre   = (const float*)d_in[34];

    float* W = (float*)d_ws;
    float* T       = W;  W += 100*NT*128;    // 3,840,000
    float* att     = W;  W += ROWS*128;
    float* satt    = W;  W += ROWS*128;
    float* xemb    = W;  W += ROWS*128;
    float* shiftx  = W;  W += ROWS*128;
    float* fh0     = W;  W += ROWS*128;      // main forget (feeds LSTM)
    float* fh1     = W;  W += ROWS*128;      // shift forget (used raw in x2)
    float* wT_in   = W;  W += 512*128;
    float* whhP_in = W;  W += 512*128;
    float* wT_fg   = W;  W += 512*128;
    float* whhP_fg = W;  W += 512*128;
    float* g_in    = W;  W += ROWS*512;
    float* g_fg    = W;  W += ROWS*512;
    float* h_in    = W;  W += ROWS*128;
    float* h_fg    = W;  W += ROWS*128;

    hipLaunchKernelGGL(k_transpose, dim3(1024), dim3(256), 0, stream,
        wih_in, wih_fg, whh_in, whh_fg, wT_in, wT_fg, whhP_in, whhP_fg);
    hipLaunchKernelGGL(k_tprep, dim3(100, 10), dim3(256), 0, stream, Es, Wc, Wp, T);
    hipLaunchKernelGGL(k_attn, dim3(ROWS, 2), dim3(128), 0, stream,
        q, c, sq, sc, Eq, Es, att, satt);
    hipLaunchKernelGGL(k_proj, dim3(200), dim3(128), 0, stream,
        q, r, sq, Eq, Er, att, satt, Wl2, bl2, Wl3, bl3, xemb, shiftx);
    hipLaunchKernelGGL(k_fh, dim3(ROWS, 2), dim3(128), 0, stream,
        c, rg, pc, ac, sc, srg, spc, sac, T, bpre, fh0, fh1);
    hipLaunchKernelGGL(k_gates, dim3(100, 2), dim3(256), 0, stream,
        xemb, fh0, wT_in, wT_fg, bih_in, bhh_in, bih_fg, bhh_fg, g_in, g_fg);
    hipLaunchKernelGGL(k_lstm, dim3(50, 2), dim3(256), 0, stream,
        g_in, g_fg, whhP_in, whhP_fg, h_in, h_fg);
    hipLaunchKernelGGL(k_final, dim3(200), dim3(128), 0, stream,
        shiftx, h_in, fh1, h_fg, Wfc4, bfc4, Wfc5, bfc5, Wfc3, bfc3, (float*)d_out);
}

// Round 3
// 293.683 us; speedup vs baseline: 1.3133x; 1.1193x over previous
//
#include <hip/hip_runtime.h>
#include <hip/hip_bf16.h>
#include <math.h>

#define BB   8
#define LL   200
#define MM   4
#define SS   100
#define DD   128
#define FF   4
#define NT   300
#define ROWS (BB*LL)   // 1600
#define JT   32        // j-tile for k_tprep

__device__ __forceinline__ float sigf(float x){ return 1.f/(1.f+expf(-x)); }

// ---------------------------------------------------------------------------
// Weight prep: all four [512,128] matrices -> paired layout
//   dst[(k*256 + p)*2 + c] = src[(p + 256*c)*128 + k]
// so thread p's two gate columns (p, p+256) at depth k are ONE float2 load.
__global__ void __launch_bounds__(256) k_transpose(
    const float* __restrict__ a0, const float* __restrict__ a1,
    const float* __restrict__ a2, const float* __restrict__ a3,
    float* __restrict__ o0, float* __restrict__ o1,
    float* __restrict__ o2, float* __restrict__ o3)
{
    int bid = blockIdx.x;
    int mat = bid >> 8;                           // 256 blocks per matrix
    int o   = ((bid & 255) << 8) + threadIdx.x;   // 0..65535
    const float* src = (mat==0)?a0:(mat==1)?a1:(mat==2)?a2:a3;
    float*       dst = (mat==0)?o0:(mat==1)?o1:(mat==2)?o2:o3;
    int k = o >> 9, rem = o & 511;
    int p = rem >> 1, cb = rem & 1;
    dst[o] = src[(p + 256*cb)*128 + k];
}

// ---------------------------------------------------------------------------
// T[s][j][t] = sum_d Wc[j,d]*Es[s,d]*Wp[s*428+d, t]  +  Wp[s*428+128+j, t]
// Register-tiled, explicit 8-deep prefetch on the Wp stream.
__global__ void __launch_bounds__(256) k_tprep(
    const float* __restrict__ Es, const float* __restrict__ Wc,
    const float* __restrict__ Wp, float* __restrict__ T)
{
    int s  = blockIdx.x;              // 0..99
    int jc = blockIdx.y;              // 0..9
    int j0 = jc * JT;
    __shared__ float WcL[JT][128];    // WcL[jj][d] = Wc[j0+jj, d] * Es[s, d]
    int tid = threadIdx.x;

    const float* es = Es + s*128;
    for (int idx = tid; idx < JT*128; idx += 256) {
        int jj = idx >> 7, d = idx & 127;
        int j = j0 + jj;
        WcL[jj][d] = (j < NT) ? Wc[j*128 + d] * es[d] : 0.f;
    }
    __syncthreads();

    const float*  wp  = Wp + (size_t)s*428*128;
    const float2* wp2 = (const float2*)wp;
    int tt = tid & 63;                // owns t = 2*tt, 2*tt+1
    int jg = tid >> 6;                // 0..3, owns 8 j's
    float2 acc[8];
    #pragma unroll
    for (int u = 0; u < 8; u++) acc[u] = make_float2(0.f, 0.f);

    for (int db = 0; db < 128; db += 8) {
        float2 wb[8];
        #pragma unroll
        for (int u = 0; u < 8; u++) wb[u] = wp2[(db+u)*64 + tt];
        #pragma unroll
        for (int u = 0; u < 8; u++) {
            #pragma unroll
            for (int j = 0; j < 8; j++) {
                float wc = WcL[jg*8 + j][db + u];
                acc[j].x += wc * wb[u].x;
                acc[j].y += wc * wb[u].y;
            }
        }
    }

    const float2* wpe = (const float2*)(wp + 128*128);   // rows 128..427
    float2* T2 = (float2*)T;
    #pragma unroll
    for (int u = 0; u < 8; u++) {
        int j = j0 + jg*8 + u;
        if (j < NT) {
            float2 b = wpe[(size_t)j*64 + tt];
            float2 o; o.x = acc[u].x + b.x; o.y = acc[u].y + b.y;
            T2[((size_t)s*NT + j)*64 + tt] = o;
        }
    }
}

// ---------------------------------------------------------------------------
// Attention, single-wave blocks, shuffle-only reduction (no barriers).
// Thread t owns cols t and t+64.
__global__ void __launch_bounds__(64) k_attn(
    const int* __restrict__ q,  const int* __restrict__ c,
    const int* __restrict__ sq, const int* __restrict__ sc,
    const float* __restrict__ Eq, const float* __restrict__ Es,
    float* __restrict__ att0, float* __restrict__ att1)
{
    int row   = blockIdx.x;
    int which = blockIdx.y;
    const int* qq = which ? sq : q;
    const int* cc = which ? sc : c;
    float* out = which ? att1 : att0;
    int t = threadIdx.x;              // 0..63

    size_t qb = (size_t)qq[row]*128;
    float eq0 = Eq[qb + t];
    float eq1 = Eq[qb + 64 + t];
    int   s[4];
    float es0[4], es1[4], d[4];
    #pragma unroll
    for (int m = 0; m < 4; m++) {
        s[m]  = cc[row*4 + m];
        es0[m] = (s[m] >= 0) ? Es[s[m]*128 + t]      : 0.f;
        es1[m] = (s[m] >= 0) ? Es[s[m]*128 + 64 + t] : 0.f;
        d[m] = eq0*es0[m] + eq1*es1[m];
    }
    #pragma unroll
    for (int off = 32; off > 0; off >>= 1) {
        #pragma unroll
        for (int m = 0; m < 4; m++) d[m] += __shfl_xor(d[m], off);
    }
    const float inv = 0.08838834764831845f;   // 1/sqrt(128)
    int   nact = 0;
    float mx = 0.f;                           // scores include >=96 zeros
    #pragma unroll
    for (int m = 0; m < 4; m++) {
        d[m] *= inv;
        if (s[m] >= 0) { nact++; mx = fmaxf(mx, d[m]); }
    }
    float Z = (float)(SS - nact) * expf(-mx);
    float w[4];
    #pragma unroll
    for (int m = 0; m < 4; m++) {
        w[m] = (s[m] >= 0) ? expf(d[m] - mx) : 0.f;
        Z += w[m];
    }
    float a0 = 0.f, a1 = 0.f;
    #pragma unroll
    for (int m = 0; m < 4; m++) {
        float ww = w[m]/Z;
        a0 += ww * es0[m];
        a1 += ww * es1[m];
    }
    out[row*128 + t]      = a0;
    out[row*128 + 64 + t] = a1;
}

// ---------------------------------------------------------------------------
// xemb = [emb_q | emb_r | att] @ W_l2 + b_l2   (K=384)   [blockIdx.y==0]
// shiftx = [emb_sq | s_att] @ W_l3 + b_l3      (K=256)   [blockIdx.y==1]
// 16 rows/block, 512 threads = 4 k-groups x 128 cols, prefetch-8, LDS reduce.
__global__ void __launch_bounds__(512) k_proj(
    const int* __restrict__ q, const int* __restrict__ r, const int* __restrict__ sq,
    const float* __restrict__ Eq, const float* __restrict__ Er,
    const float* __restrict__ att, const float* __restrict__ satt,
    const float* __restrict__ Wl2, const float* __restrict__ bl2,
    const float* __restrict__ Wl3, const float* __restrict__ bl3,
    float* __restrict__ xemb, float* __restrict__ shiftx)
{
    int which = blockIdx.y;
    int r0  = blockIdx.x * 16;
    int tid = threadIdx.x;
    int kg  = tid >> 7;       // 0..3
    int col = tid & 127;
    __shared__ float xs[16][384];
    __shared__ float part[4][16][128];

    if (!which) {
        for (int e = tid; e < 16*384; e += 512) {
            int i = e / 384, pos = e - i*384;
            int row = r0 + i;
            float v;
            if (pos < 128)      v = Eq[(size_t)q[row]*128 + pos];
            else if (pos < 256) v = Er[r[row]*128 + (pos-128)];
            else                v = att[row*128 + (pos-256)];
            xs[i][pos] = v;
        }
    } else {
        for (int e = tid; e < 16*256; e += 512) {
            int i = e >> 8, pos = e & 255;
            int row = r0 + i;
            float v;
            if (pos < 128) v = Eq[(size_t)sq[row]*128 + pos];
            else           v = satt[row*128 + (pos-128)];
            xs[i][pos] = v;
        }
    }
    __syncthreads();

    const float* Wm = which ? Wl3 : Wl2;
    int kper = which ? 64 : 96;
    int k0 = kg * kper;
    float acc[16];
    #pragma unroll
    for (int i = 0; i < 16; i++) acc[i] = 0.f;
    for (int kb = 0; kb < kper; kb += 8) {
        float wbuf[8];
        #pragma unroll
        for (int u = 0; u < 8; u++)
            wbuf[u] = Wm[(k0 + kb + u)*128 + col];
        #pragma unroll
        for (int u = 0; u < 8; u++) {
            float w = wbuf[u];
            int k = k0 + kb + u;
            #pragma unroll
            for (int i = 0; i < 16; i++)
                acc[i] += xs[i][k] * w;
        }
    }
    #pragma unroll
    for (int i = 0; i < 16; i++) part[kg][i][col] = acc[i];
    __syncthreads();

    const float* bias = which ? bl3 : bl2;
    float* out = which ? shiftx : xemb;
    for (int e = tid; e < 2048; e += 512) {
        int i = e >> 7, cc = e & 127;
        float v = bias[cc] + part[0][i][cc] + part[1][i][cc]
                           + part[2][i][cc] + part[3][i][cc];
        out[(r0+i)*128 + cc] = v;
    }
}

// ---------------------------------------------------------------------------
// fh[row,:] = b_pre + sum over active m, f of 12-row gather from T
__global__ void __launch_bounds__(128) k_fh(
    const int* __restrict__ c,  const int* __restrict__ rg,
    const int* __restrict__ pc, const int* __restrict__ ac,
    const int* __restrict__ c2, const int* __restrict__ rg2,
    const int* __restrict__ pc2,const int* __restrict__ ac2,
    const float* __restrict__ T, const float* __restrict__ bpre,
    float* __restrict__ fh0, float* __restrict__ fh1)
{
    int row   = blockIdx.x;
    int which = blockIdx.y;
    const int* C  = which ? c2  : c;
    const int* RG = which ? rg2 : rg;
    const int* PC = which ? pc2 : pc;
    const int* AC = which ? ac2 : ac;
    float* out = which ? fh1 : fh0;
    int t = threadIdx.x;

    float acc = bpre[t];
    for (int m = 0; m < 4; m++) {
        int s = C[row*4 + m];
        if (s < 0) continue;                  // block-uniform branch
        int rgv = RG[row*4 + m];
        const float* Ts = T + (size_t)s*NT*128;
        #pragma unroll
        for (int f = 0; f < 4; f++) {
            int j1 = f*25 + rgv;
            int j2 = 100 + f*25 + PC[(row*4+m)*4 + f];
            int j3 = 200 + f*25 + AC[(row*4+m)*4 + f];
            acc += Ts[j1*128 + t] + Ts[j2*128 + t] + Ts[j3*128 + t];
        }
    }
    out[row*128 + t] = acc;
}

// ---------------------------------------------------------------------------
// gates_x = X @ wih.T + (bih + bhh) : [1600,128] @ [128,512], paired W.
// 8 rows/block, grid (200,2), prefetch-8, 16 FMA per float2 load.
__global__ void __launch_bounds__(256) k_gates(
    const float* __restrict__ xemb, const float* __restrict__ fh,
    const float* __restrict__ wP_in, const float* __restrict__ wP_fg,
    const float* __restrict__ bih_in, const float* __restrict__ bhh_in,
    const float* __restrict__ bih_fg, const float* __restrict__ bhh_fg,
    float* __restrict__ g_in, float* __restrict__ g_fg)
{
    int which = blockIdx.y;
    const float*  X   = which ? fh : xemb;
    const float2* Wp2 = (const float2*)(which ? wP_fg : wP_in);
    const float*  b1  = which ? bih_fg : bih_in;
    const float*  b2  = which ? bhh_fg : bhh_in;
    float* G = which ? g_fg : g_in;

    int r0  = blockIdx.x * 8;
    int tid = threadIdx.x;
    __shared__ float xl[8][128];
    for (int e = tid; e < 8*128; e += 256)
        xl[e>>7][e&127] = X[(size_t)r0*128 + e];
    __syncthreads();

    int p = tid;                              // gate cols p, p+256
    float a0[8], a1[8];
    #pragma unroll
    for (int i = 0; i < 8; i++) { a0[i] = 0.f; a1[i] = 0.f; }
    for (int kb = 0; kb < 128; kb += 8) {
        float2 wbuf[8];
        #pragma unroll
        for (int u = 0; u < 8; u++) wbuf[u] = Wp2[(kb+u)*256 + p];
        #pragma unroll
        for (int u = 0; u < 8; u++) {
            #pragma unroll
            for (int i = 0; i < 8; i++) {
                float xv = xl[i][kb+u];
                a0[i] += xv * wbuf[u].x;
                a1[i] += xv * wbuf[u].y;
            }
        }
    }
    float bb0 = b1[p] + b2[p];
    float bb1 = b1[p+256] + b2[p+256];
    #pragma unroll
    for (int i = 0; i < 8; i++) {
        G[(size_t)(r0+i)*512 + p]       = a0[i] + bb0;
        G[(size_t)(r0+i)*512 + p + 256] = a1[i] + bb1;
    }
}

// ---------------------------------------------------------------------------
// LSTM over 8 steps. 512 threads: rg=tid>>8 owns 2 rows, p=tid&255 pair-col.
// Prefetch-8 on the whhP stream.
__global__ void __launch_bounds__(512) k_lstm(
    const float* __restrict__ g_in, const float* __restrict__ g_fg,
    const float* __restrict__ whhP_in, const float* __restrict__ whhP_fg,
    float* __restrict__ h_in_out, float* __restrict__ h_fg_out)
{
    int which = blockIdx.y;
    const float*  GX  = which ? g_fg : g_in;
    const float2* Wp2 = (const float2*)(which ? whhP_fg : whhP_in);
    float* OUT = which ? h_fg_out : h_in_out;

    int row0 = blockIdx.x * 4;                // grid.x = 50
    int tid  = threadIdx.x;
    int rg   = tid >> 8;                      // 0..1
    int p    = tid & 255;
    int ra = rg*2, rb = rg*2 + 1;
    __shared__ float h[4][128], cs[4][128], g[4][512];
    if (tid < 512) {
        int e = tid;
        h[e>>7][e&127]  = 0.f;
        cs[e>>7][e&127] = 0.f;
    }
    __syncthreads();

    for (int t = 0; t < 8; t++) {
        float a0 = GX[(size_t)(t*200 + row0 + ra)*512 + p];
        float a1 = GX[(size_t)(t*200 + row0 + ra)*512 + p + 256];
        float b0 = GX[(size_t)(t*200 + row0 + rb)*512 + p];
        float b1 = GX[(size_t)(t*200 + row0 + rb)*512 + p + 256];
        for (int kb = 0; kb < 128; kb += 8) {
            float2 wbuf[8];
            #pragma unroll
            for (int u = 0; u < 8; u++) wbuf[u] = Wp2[(kb+u)*256 + p];
            #pragma unroll
            for (int u = 0; u < 8; u++) {
                float ha = h[ra][kb+u], hb = h[rb][kb+u];
                a0 += ha * wbuf[u].x;
                a1 += ha * wbuf[u].y;
                b0 += hb * wbuf[u].x;
                b1 += hb * wbuf[u].y;
            }
        }
        __syncthreads();                      // all h reads done
        g[ra][p] = a0; g[ra][p+256] = a1;
        g[rb][p] = b0; g[rb][p+256] = b1;
        __syncthreads();                      // gates visible
        {
            int rr = tid >> 7, d = tid & 127;
            float gi = g[rr][d], gf = g[rr][128+d], gg = g[rr][256+d], go = g[rr][384+d];
            float c_new = sigf(gf)*cs[rr][d] + sigf(gi)*tanhf(gg);
            float h_new = sigf(go)*tanhf(c_new);
            cs[rr][d] = c_new;
            h[rr][d]  = h_new;
            OUT[(size_t)(t*200 + row0 + rr)*128 + d] = h_new;
        }
        __syncthreads();                      // state updated before next step
    }
}

// ---------------------------------------------------------------------------
// x1 = relu([shiftx|h_in]@W_fc4+b4); x2 = relu([fh1|h_fg]@W_fc5+b5)
// y = sigmoid([x1|x2]@W_fc3+b3).  8 rows/block, 2-way k-split, prefetch-8.
__global__ void __launch_bounds__(256) k_final(
    const float* __restrict__ shiftx, const float* __restrict__ h_in,
    const float* __restrict__ fh_shift, const float* __restrict__ h_fg,
    const float* __restrict__ Wfc4, const float* __restrict__ bfc4,
    const float* __restrict__ Wfc5, const float* __restrict__ bfc5,
    const float* __restrict__ Wfc3, const float* __restrict__ bfc3,
    float* __restrict__ out)
{
    int r0  = blockIdx.x * 8;                 // grid 200
    int tid = threadIdx.x;
    int kg  = tid >> 7;                       // 0..1
    int col = tid & 127;
    __shared__ float xa[8][256], xb[8][256];
    __shared__ float part[2][8][128];

    for (int e = tid; e < 8*256; e += 256) {
        int i = e >> 8, pos = e & 255;
        int row = r0 + i;
        xa[i][pos] = (pos < 128) ? shiftx[row*128 + pos]    : h_in[row*128 + pos-128];
        xb[i][pos] = (pos < 128) ? fh_shift[row*128 + pos]  : h_fg[row*128 + pos-128];
    }
    __syncthreads();

    float acc4[8], acc5[8];
    #pragma unroll
    for (int i = 0; i < 8; i++) { acc4[i] = 0.f; acc5[i] = 0.f; }
    int k0 = kg * 128;
    for (int kb = 0; kb < 128; kb += 8) {
        float w4[8], w5[8];
        #pragma unroll
        for (int u = 0; u < 8; u++) {
            w4[u] = Wfc4[(k0+kb+u)*128 + col];
            w5[u] = Wfc5[(k0+kb+u)*128 + col];
        }
        #pragma unroll
        for (int u = 0; u < 8; u++) {
            int k = k0 + kb + u;
            #pragma unroll
            for (int i = 0; i < 8; i++) {
                acc4[i] += xa[i][k] * w4[u];
                acc5[i] += xb[i][k] * w5[u];
            }
        }
    }

    // reduce fc4 partials -> x1 (4 outputs/thread, in regs)
    #pragma unroll
    for (int i = 0; i < 8; i++) part[kg][i][col] = acc4[i];
    __syncthreads();
    float x1r[4];
    #pragma unroll
    for (int j = 0; j < 4; j++) {
        int e = tid + 256*j;
        int i = e >> 7;
        x1r[j] = fmaxf(part[0][i][col] + part[1][i][col] + bfc4[col], 0.f);
    }
    __syncthreads();                          // done reading before overwrite
    #pragma unroll
    for (int i = 0; i < 8; i++) part[kg][i][col] = acc5[i];
    __syncthreads();
    float x2r[4];
    #pragma unroll
    for (int j = 0; j < 4; j++) {
        int e = tid + 256*j;
        int i = e >> 7;
        x2r[j] = fmaxf(part[0][i][col] + part[1][i][col] + bfc5[col], 0.f);
    }
    __syncthreads();                          // done reading before overwrite

    // fc3 contributions into reused LDS, then per-row shuffle reduce
    float* cont = &part[0][0][0];             // [8][128]
    float w3a = Wfc3[col], w3b = Wfc3[128 + col];
    #pragma unroll
    for (int j = 0; j < 4; j++) {
        int e = tid + 256*j;
        int i = e >> 7;
        cont[i*128 + col] = x1r[j]*w3a + x2r[j]*w3b;
    }
    __syncthreads();
    int row = tid >> 5, l = tid & 31;
    float sum = cont[row*128 + l] + cont[row*128 + l + 32]
              + cont[row*128 + l + 64] + cont[row*128 + l + 96];
    #pragma unroll
    for (int off = 16; off > 0; off >>= 1) sum += __shfl_xor(sum, off);
    if (l == 0) out[r0 + row] = 1.f/(1.f + expf(-(sum + bfc3[0])));
}

// ---------------------------------------------------------------------------
extern "C" void kernel_launch(void* const* d_in, const int* in_sizes, int n_in,
                              void* d_out, int out_size, void* d_ws, size_t ws_size,
                              hipStream_t stream)
{
    const int*   q      = (const int*)d_in[0];
    const int*   c      = (const int*)d_in[1];
    const int*   sq     = (const int*)d_in[2];
    const int*   sc     = (const int*)d_in[3];
    const int*   r      = (const int*)d_in[4];
    const int*   rg     = (const int*)d_in[5];
    const int*   pc     = (const int*)d_in[6];
    const int*   ac     = (const int*)d_in[7];
    const int*   srg    = (const int*)d_in[8];
    const int*   spc    = (const int*)d_in[9];
    const int*   sac    = (const int*)d_in[10];
    const float* Es     = (const float*)d_in[11];
    const float* Eq     = (const float*)d_in[12];
    const float* Er     = (const float*)d_in[13];
    const float* wih_in = (const float*)d_in[14];
    const float* whh_in = (const float*)d_in[15];
    const float* bih_in = (const float*)d_in[16];
    const float* bhh_in = (const float*)d_in[17];
    const float* wih_fg = (const float*)d_in[18];
    const float* whh_fg = (const float*)d_in[19];
    const float* bih_fg = (const float*)d_in[20];
    const float* bhh_fg = (const float*)d_in[21];
    const float* Wl2    = (const float*)d_in[22];
    const float* bl2    = (const float*)d_in[23];
    const float* Wl3    = (const float*)d_in[24];
    const float* bl3    = (const float*)d_in[25];
    const float* Wfc3   = (const float*)d_in[26];
    const float* bfc3   = (const float*)d_in[27];
    const float* Wfc4   = (const float*)d_in[28];
    const float* bfc4   = (const float*)d_in[29];
    const float* Wfc5   = (const float*)d_in[30];
    const float* bfc5   = (const float*)d_in[31];
    const float* Wc     = (const float*)d_in[32];
    const float* Wp     = (const float*)d_in[33];
    const float* bpre   = (const float*)d_in[34];

    float* W = (float*)d_ws;
    float* T       = W;  W += 100*NT*128;    // 3,840,000
    float* att     = W;  W += ROWS*128;
    float* satt    = W;  W += ROWS*128;
    float* xemb    = W;  W += ROWS*128;
    float* shiftx  = W;  W += ROWS*128;
    float* fh0     = W;  W += ROWS*128;      // main forget (feeds LSTM)
    float* fh1     = W;  W += ROWS*128;      // shift forget (used raw in x2)
    float* wP_in   = W;  W += 512*128;
    float* whhP_in = W;  W += 512*128;
    float* wP_fg   = W;  W += 512*128;
    float* whhP_fg = W;  W += 512*128;
    float* g_in    = W;  W += ROWS*512;
    float* g_fg    = W;  W += ROWS*512;
    float* h_in    = W;  W += ROWS*128;
    float* h_fg    = W;  W += ROWS*128;

    hipLaunchKernelGGL(k_transpose, dim3(1024), dim3(256), 0, stream,
        wih_in, wih_fg, whh_in, whh_fg, wP_in, wP_fg, whhP_in, whhP_fg);
    hipLaunchKernelGGL(k_tprep, dim3(100, 10), dim3(256), 0, stream, Es, Wc, Wp, T);
    hipLaunchKernelGGL(k_attn, dim3(ROWS, 2), dim3(64), 0, stream,
        q, c, sq, sc, Eq, Es, att, satt);
    hipLaunchKernelGGL(k_proj, dim3(100, 2), dim3(512), 0, stream,
        q, r, sq, Eq, Er, att, satt, Wl2, bl2, Wl3, bl3, xemb, shiftx);
    hipLaunchKernelGGL(k_fh, dim3(ROWS, 2), dim3(128), 0, stream,
        c, rg, pc, ac, sc, srg, spc, sac, T, bpre, fh0, fh1);
    hipLaunchKernelGGL(k_gates, dim3(200, 2), dim3(256), 0, stream,
        xemb, fh0, wP_in, wP_fg, bih_in, bhh_in, bih_fg, bhh_fg, g_in, g_fg);
    hipLaunchKernelGGL(k_lstm, dim3(50, 2), dim3(512), 0, stream,
        g_in, g_fg, whhP_in, whhP_fg, h_in, h_fg);
    hipLaunchKernelGGL(k_final, dim3(200), dim3(256), 0, stream,
        shiftx, h_in, fh1, h_fg, Wfc4, bfc4, Wfc5, bfc5, Wfc3, bfc3, (float*)d_out);
}

// Round 7
// 232.505 us; speedup vs baseline: 1.6588x; 1.2631x over previous
//
#include <hip/hip_runtime.h>
#include <hip/hip_bf16.h>
#include <math.h>

#define BB   8
#define LL   200
#define MM   4
#define SS   100
#define DD   128
#define FF   4
#define NT   300
#define ROWS (BB*LL)   // 1600
#define JT   32        // j-tile for tprep

// stage1 block ranges
#define NB_TR  128
#define NB_TP  1000
#define NB_AT  800     // 3200 (row,which) tasks / 4 waves per block
// stage2 block ranges
#define NB_PJ  400     // proj: 4 rows/block
#define NB_FH  1600    // fh: 2 tasks/block

__device__ __forceinline__ float sigf(float x){ return 1.f/(1.f+expf(-x)); }

// ===========================================================================
// STAGE 1: transpose (4 weight mats -> [128][512]) | tprep | attn
// ===========================================================================
__global__ void __launch_bounds__(256) k_stage1(
    // transpose
    const float* __restrict__ wih_in, const float* __restrict__ wih_fg,
    const float* __restrict__ whh_in, const float* __restrict__ whh_fg,
    float* __restrict__ wT_in, float* __restrict__ wT_fg,
    float* __restrict__ whhT_in, float* __restrict__ whhT_fg,
    // tprep
    const float* __restrict__ Es, const float* __restrict__ Wc,
    const float* __restrict__ Wp, float* __restrict__ T,
    // attn
    const int* __restrict__ q,  const int* __restrict__ c,
    const int* __restrict__ sq, const int* __restrict__ sc,
    const float* __restrict__ Eq,
    float* __restrict__ att0, float* __restrict__ att1)
{
    __shared__ float WcL[JT][128];
    int b   = blockIdx.x;
    int tid = threadIdx.x;

    if (b < NB_TR) {
        // ---- transpose: dst[k*512+g] = src[g*128+k], 4 mats x 65536 ----
        for (int e = b*256 + tid; e < 4*65536; e += NB_TR*256) {
            int mat = e >> 16, o = e & 65535;
            int k = o >> 9, g = o & 511;
            const float* src = (mat==0)?wih_in:(mat==1)?wih_fg:(mat==2)?whh_in:whh_fg;
            float*       dst = (mat==0)?wT_in:(mat==1)?wT_fg:(mat==2)?whhT_in:whhT_fg;
            dst[o] = src[g*128 + k];
        }
        return;
    }
    if (b < NB_TR + NB_TP) {
        // ---- tprep: T[s][j][t] = sum_d Wc[j,d]*Es[s,d]*Wp[s*428+d,t] + Wp[s*428+128+j,t]
        int bb2 = b - NB_TR;
        int s  = bb2 / 10;
        int jc = bb2 - s*10;
        int j0 = jc * JT;
        const float* es = Es + s*128;
        for (int idx = tid; idx < JT*128; idx += 256) {
            int jj = idx >> 7, d = idx & 127;
            int j = j0 + jj;
            WcL[jj][d] = (j < NT) ? Wc[j*128 + d] * es[d] : 0.f;
        }
        __syncthreads();

        const float*  wp  = Wp + (size_t)s*428*128;
        const float2* wp2 = (const float2*)wp;
        int tt = tid & 63;
        int jg = tid >> 6;
        float2 acc[8];
        #pragma unroll
        for (int u = 0; u < 8; u++) acc[u] = make_float2(0.f, 0.f);
        for (int db = 0; db < 128; db += 8) {
            float2 wb[8];
            #pragma unroll
            for (int u = 0; u < 8; u++) wb[u] = wp2[(db+u)*64 + tt];
            #pragma unroll
            for (int u = 0; u < 8; u++) {
                #pragma unroll
                for (int j = 0; j < 8; j++) {
                    float wc = WcL[jg*8 + j][db + u];
                    acc[j].x += wc * wb[u].x;
                    acc[j].y += wc * wb[u].y;
                }
            }
        }
        const float2* wpe = (const float2*)(wp + 128*128);
        float2* T2 = (float2*)T;
        #pragma unroll
        for (int u = 0; u < 8; u++) {
            int j = j0 + jg*8 + u;
            if (j < NT) {
                float2 bv = wpe[(size_t)j*64 + tt];
                float2 o; o.x = acc[u].x + bv.x; o.y = acc[u].y + bv.y;
                T2[((size_t)s*NT + j)*64 + tt] = o;
            }
        }
        return;
    }
    // ---- attn: 4 waves/block, each wave = one (row,which) task ----
    {
        int wv   = tid >> 6;
        int lane = tid & 63;
        int task = (b - NB_TR - NB_TP)*4 + wv;   // 0..3199
        int row   = task >> 1;
        int which = task & 1;
        const int* qq = which ? sq : q;
        const int* cc = which ? sc : c;
        float* out = which ? att1 : att0;

        size_t qb = (size_t)qq[row]*128;
        float eq0 = Eq[qb + lane];
        float eq1 = Eq[qb + 64 + lane];
        int   s[4];
        float es0[4], es1[4], d[4];
        #pragma unroll
        for (int m = 0; m < 4; m++) {
            s[m]  = cc[row*4 + m];
            es0[m] = (s[m] >= 0) ? Es[s[m]*128 + lane]      : 0.f;
            es1[m] = (s[m] >= 0) ? Es[s[m]*128 + 64 + lane] : 0.f;
            d[m] = eq0*es0[m] + eq1*es1[m];
        }
        #pragma unroll
        for (int off = 32; off > 0; off >>= 1) {
            #pragma unroll
            for (int m = 0; m < 4; m++) d[m] += __shfl_xor(d[m], off);
        }
        const float inv = 0.08838834764831845f;   // 1/sqrt(128)
        int   nact = 0;
        float mx = 0.f;
        #pragma unroll
        for (int m = 0; m < 4; m++) {
            d[m] *= inv;
            if (s[m] >= 0) { nact++; mx = fmaxf(mx, d[m]); }
        }
        float Z = (float)(SS - nact) * expf(-mx);
        float w[4];
        #pragma unroll
        for (int m = 0; m < 4; m++) {
            w[m] = (s[m] >= 0) ? expf(d[m] - mx) : 0.f;
            Z += w[m];
        }
        float a0 = 0.f, a1 = 0.f;
        #pragma unroll
        for (int m = 0; m < 4; m++) {
            float ww = w[m]/Z;
            a0 += ww * es0[m];
            a1 += ww * es1[m];
        }
        out[row*128 + lane]      = a0;
        out[row*128 + 64 + lane] = a1;
    }
}

// ===========================================================================
// STAGE 2: proj (xemb + shiftx) | fh (both forget gathers)
// ===========================================================================
__global__ void __launch_bounds__(256) k_stage2(
    // proj
    const int* __restrict__ q, const int* __restrict__ r, const int* __restrict__ sq,
    const float* __restrict__ Eq, const float* __restrict__ Er,
    const float* __restrict__ att, const float* __restrict__ satt,
    const float* __restrict__ Wl2, const float* __restrict__ bl2,
    const float* __restrict__ Wl3, const float* __restrict__ bl3,
    float* __restrict__ xemb, float* __restrict__ shiftx,
    // fh
    const int* __restrict__ c,  const int* __restrict__ rg,
    const int* __restrict__ pc, const int* __restrict__ ac,
    const int* __restrict__ sc, const int* __restrict__ srg,
    const int* __restrict__ spc,const int* __restrict__ sac,
    const float* __restrict__ T, const float* __restrict__ bpre,
    float* __restrict__ fh0, float* __restrict__ fh1)
{
    __shared__ float xs1[4][384];
    __shared__ float xs2[4][256];
    __shared__ float part[2][4][128];
    int b   = blockIdx.x;
    int tid = threadIdx.x;

    if (b < NB_PJ) {
        // ---- proj: 4 rows/block ----
        int r0 = b*4;
        for (int e = tid; e < 4*384; e += 256) {
            int i = e / 384, pos = e - i*384;
            int row = r0 + i;
            float v;
            if (pos < 128)      v = Eq[(size_t)q[row]*128 + pos];
            else if (pos < 256) v = Er[r[row]*128 + (pos-128)];
            else                v = att[row*128 + (pos-256)];
            xs1[i][pos] = v;
        }
        for (int e = tid; e < 4*256; e += 256) {
            int i = e >> 8, pos = e & 255;
            int row = r0 + i;
            xs2[i][pos] = (pos < 128) ? Eq[(size_t)sq[row]*128 + pos]
                                      : satt[row*128 + (pos-128)];
        }
        __syncthreads();

        int kg  = tid >> 7;
        int col = tid & 127;
        // l2: K=384, halves of 192
        {
            float acc[4];
            #pragma unroll
            for (int i = 0; i < 4; i++) acc[i] = 0.f;
            int k0 = kg*192;
            for (int kb = 0; kb < 192; kb += 8) {
                float wb[8];
                #pragma unroll
                for (int u = 0; u < 8; u++) wb[u] = Wl2[(k0+kb+u)*128 + col];
                #pragma unroll
                for (int u = 0; u < 8; u++) {
                    #pragma unroll
                    for (int i = 0; i < 4; i++) acc[i] += xs1[i][k0+kb+u]*wb[u];
                }
            }
            #pragma unroll
            for (int i = 0; i < 4; i++) part[kg][i][col] = acc[i];
        }
        __syncthreads();
        for (int e = tid; e < 512; e += 256) {
            int i = e >> 7, cc2 = e & 127;
            xemb[(r0+i)*128 + cc2] = bl2[cc2] + part[0][i][cc2] + part[1][i][cc2];
        }
        __syncthreads();
        // l3: K=256, halves of 128
        {
            float acc[4];
            #pragma unroll
            for (int i = 0; i < 4; i++) acc[i] = 0.f;
            int k0 = kg*128;
            for (int kb = 0; kb < 128; kb += 8) {
                float wb[8];
                #pragma unroll
                for (int u = 0; u < 8; u++) wb[u] = Wl3[(k0+kb+u)*128 + col];
                #pragma unroll
                for (int u = 0; u < 8; u++) {
                    #pragma unroll
                    for (int i = 0; i < 4; i++) acc[i] += xs2[i][k0+kb+u]*wb[u];
                }
            }
            #pragma unroll
            for (int i = 0; i < 4; i++) part[kg][i][col] = acc[i];
        }
        __syncthreads();
        for (int e = tid; e < 512; e += 256) {
            int i = e >> 7, cc2 = e & 127;
            shiftx[(r0+i)*128 + cc2] = bl3[cc2] + part[0][i][cc2] + part[1][i][cc2];
        }
        return;
    }
    // ---- fh: 2 tasks/block (128 threads each) ----
    {
        int u     = (b - NB_PJ)*2 + (tid >> 7);   // 0..3199
        int which = u & 1;
        int row   = u >> 1;
        int t     = tid & 127;
        const int* C  = which ? sc  : c;
        const int* RG = which ? srg : rg;
        const int* PC = which ? spc : pc;
        const int* AC = which ? sac : ac;
        float* out = which ? fh1 : fh0;

        float acc = bpre[t];
        for (int m = 0; m < 4; m++) {
            int s = C[row*4 + m];
            if (s < 0) continue;
            int rgv = RG[row*4 + m];
            const float* Ts = T + (size_t)s*NT*128;
            #pragma unroll
            for (int f = 0; f < 4; f++) {
                int j1 = f*25 + rgv;
                int j2 = 100 + f*25 + PC[(row*4+m)*4 + f];
                int j3 = 200 + f*25 + AC[(row*4+m)*4 + f];
                acc += Ts[j1*128 + t] + Ts[j2*128 + t] + Ts[j3*128 + t];
            }
        }
        out[row*128 + t] = acc;
    }
}

// ===========================================================================
// LSTM with fused gates. grid (100, 2), 512 threads.
// Thread owns gate col p = tid. whh col held in VGPRs across all 8 steps;
// h broadcast from LDS (same-address -> conflict-free). Gates g = x@wihT+b
// computed once upfront into LDS.
// ===========================================================================
__global__ void __launch_bounds__(512) k_lstm(
    const float* __restrict__ xemb, const float* __restrict__ fh,
    const float* __restrict__ wT_in, const float* __restrict__ wT_fg,
    const float* __restrict__ whhT_in, const float* __restrict__ whhT_fg,
    const float* __restrict__ bih_in, const float* __restrict__ bhh_in,
    const float* __restrict__ bih_fg, const float* __restrict__ bhh_fg,
    float* __restrict__ h_in_out, float* __restrict__ h_fg_out)
{
    int which = blockIdx.y;
    const float* X  = which ? fh      : xemb;
    const float* WI = which ? wT_fg   : wT_in;
    const float* WH = which ? whhT_fg : whhT_in;
    const float* B1 = which ? bih_fg  : bih_in;
    const float* B2 = which ? bhh_fg  : bhh_in;
    float* OUT = which ? h_fg_out : h_in_out;

    int l0  = blockIdx.x * 2;      // 2 rows/block
    int tid = threadIdx.x;         // gate col p

    __shared__ float xr[16][128];  // [(t*2+rr)][d]
    __shared__ float gb[16][512];  // x-gates for all steps
    __shared__ float h[2][128], cs[2][128], gl[2][512];

    for (int e = tid; e < 2048; e += 512) {
        int i = e >> 7, d = e & 127;
        int t = i >> 1, rr = i & 1;
        xr[i][d] = X[(size_t)(t*200 + l0 + rr)*128 + d];
    }
    if (tid < 256) { h[tid>>7][tid&127] = 0.f; cs[tid>>7][tid&127] = 0.f; }
    __syncthreads();

    // gates: gb[i][p] = bb + sum_k xr[i][k] * WI[k*512+p]
    float bb = B1[tid] + B2[tid];
    {
        float a[16];
        #pragma unroll
        for (int i = 0; i < 16; i++) a[i] = bb;
        for (int kb = 0; kb < 128; kb += 8) {
            float wv[8];
            #pragma unroll
            for (int u = 0; u < 8; u++) wv[u] = WI[(kb+u)*512 + tid];
            #pragma unroll
            for (int u = 0; u < 8; u++) {
                #pragma unroll
                for (int i = 0; i < 16; i++) a[i] += xr[i][kb+u]*wv[u];
            }
        }
        #pragma unroll
        for (int i = 0; i < 16; i++) gb[i][tid] = a[i];
    }

    // whh column -> registers (static indices => VGPRs)
    float w[128];
    #pragma unroll
    for (int k = 0; k < 128; k++) w[k] = WH[k*512 + tid];
    __syncthreads();

    // recurrence over 8 steps; no global loads inside
    for (int t = 0; t < 8; t++) {
        float a0 = gb[t*2 + 0][tid];
        float a1 = gb[t*2 + 1][tid];
        #pragma unroll
        for (int k = 0; k < 128; k++) {
            float h0 = h[0][k], h1 = h[1][k];   // LDS broadcast
            a0 += h0*w[k];
            a1 += h1*w[k];
        }
        gl[0][tid] = a0;
        gl[1][tid] = a1;
        __syncthreads();
        if (tid < 256) {
            int rr = tid >> 7, d = tid & 127;
            float gi = gl[rr][d], gf = gl[rr][128+d], gg = gl[rr][256+d], go = gl[rr][384+d];
            float cn = sigf(gf)*cs[rr][d] + sigf(gi)*tanhf(gg);
            float hn = sigf(go)*tanhf(cn);
            cs[rr][d] = cn;
            h[rr][d]  = hn;
            OUT[(size_t)(t*200 + l0 + rr)*128 + d] = hn;
        }
        __syncthreads();
    }
}

// ===========================================================================
// FINAL: x1=relu([shiftx|h_in]@W4+b4); x2=relu([fh1|h_fg]@W5+b5);
// y=sigmoid([x1|x2]@W3+b3). 4 rows/block, 400 blocks, 256 thr.
// ===========================================================================
__global__ void __launch_bounds__(256) k_final(
    const float* __restrict__ shiftx, const float* __restrict__ h_in,
    const float* __restrict__ fh_shift, const float* __restrict__ h_fg,
    const float* __restrict__ Wfc4, const float* __restrict__ bfc4,
    const float* __restrict__ Wfc5, const float* __restrict__ bfc5,
    const float* __restrict__ Wfc3, const float* __restrict__ bfc3,
    float* __restrict__ out)
{
    int r0  = blockIdx.x * 4;
    int tid = threadIdx.x;
    int kg  = tid >> 7;
    int col = tid & 127;
    __shared__ float xa[4][256], xb[4][256];
    __shared__ float part[2][4][128];

    for (int e = tid; e < 4*256; e += 256) {
        int i = e >> 8, pos = e & 255;
        int row = r0 + i;
        xa[i][pos] = (pos < 128) ? shiftx[row*128 + pos]   : h_in[row*128 + pos-128];
        xb[i][pos] = (pos < 128) ? fh_shift[row*128 + pos] : h_fg[row*128 + pos-128];
    }
    __syncthreads();

    float acc4[4], acc5[4];
    #pragma unroll
    for (int i = 0; i < 4; i++) { acc4[i] = 0.f; acc5[i] = 0.f; }
    int k0 = kg * 128;
    for (int kb = 0; kb < 128; kb += 8) {
        float w4[8], w5[8];
        #pragma unroll
        for (int u = 0; u < 8; u++) {
            w4[u] = Wfc4[(k0+kb+u)*128 + col];
            w5[u] = Wfc5[(k0+kb+u)*128 + col];
        }
        #pragma unroll
        for (int u = 0; u < 8; u++) {
            int k = k0 + kb + u;
            #pragma unroll
            for (int i = 0; i < 4; i++) {
                acc4[i] += xa[i][k] * w4[u];
                acc5[i] += xb[i][k] * w5[u];
            }
        }
    }

    #pragma unroll
    for (int i = 0; i < 4; i++) part[kg][i][col] = acc4[i];
    __syncthreads();
    float x1r[2];
    #pragma unroll
    for (int j = 0; j < 2; j++) {
        int e = tid + 256*j;
        int i = e >> 7, cc2 = e & 127;
        x1r[j] = fmaxf(part[0][i][cc2] + part[1][i][cc2] + bfc4[cc2], 0.f);
    }
    __syncthreads();
    #pragma unroll
    for (int i = 0; i < 4; i++) part[kg][i][col] = acc5[i];
    __syncthreads();
    float x2r[2];
    #pragma unroll
    for (int j = 0; j < 2; j++) {
        int e = tid + 256*j;
        int i = e >> 7, cc2 = e & 127;
        x2r[j] = fmaxf(part[0][i][cc2] + part[1][i][cc2] + bfc5[cc2], 0.f);
    }
    __syncthreads();

    // fc3 contributions; reuse part[0] as cont[4][128]
    float* cont = &part[0][0][0];
    #pragma unroll
    for (int j = 0; j < 2; j++) {
        int e = tid + 256*j;
        int i = e >> 7, cc2 = e & 127;
        cont[i*128 + cc2] = x1r[j]*Wfc3[cc2] + x2r[j]*Wfc3[128 + cc2];
    }
    __syncthreads();
    int wv = tid >> 6, lane = tid & 63;      // wave wv handles row wv
    float sum = cont[wv*128 + lane] + cont[wv*128 + lane + 64];
    #pragma unroll
    for (int off = 32; off > 0; off >>= 1) sum += __shfl_xor(sum, off);
    if (lane == 0) out[r0 + wv] = 1.f/(1.f + expf(-(sum + bfc3[0])));
}

// ---------------------------------------------------------------------------
extern "C" void kernel_launch(void* const* d_in, const int* in_sizes, int n_in,
                              void* d_out, int out_size, void* d_ws, size_t ws_size,
                              hipStream_t stream)
{
    const int*   q      = (const int*)d_in[0];
    const int*   c      = (const int*)d_in[1];
    const int*   sq     = (const int*)d_in[2];
    const int*   sc     = (const int*)d_in[3];
    const int*   r      = (const int*)d_in[4];
    const int*   rg     = (const int*)d_in[5];
    const int*   pc     = (const int*)d_in[6];
    const int*   ac     = (const int*)d_in[7];
    const int*   srg    = (const int*)d_in[8];
    const int*   spc    = (const int*)d_in[9];
    const int*   sac    = (const int*)d_in[10];
    const float* Es     = (const float*)d_in[11];
    const float* Eq     = (const float*)d_in[12];
    const float* Er     = (const float*)d_in[13];
    const float* wih_in = (const float*)d_in[14];
    const float* whh_in = (const float*)d_in[15];
    const float* bih_in = (const float*)d_in[16];
    const float* bhh_in = (const float*)d_in[17];
    const float* wih_fg = (const float*)d_in[18];
    const float* whh_fg = (const float*)d_in[19];
    const float* bih_fg = (const float*)d_in[20];
    const float* bhh_fg = (const float*)d_in[21];
    const float* Wl2    = (const float*)d_in[22];
    const float* bl2    = (const float*)d_in[23];
    const float* Wl3    = (const float*)d_in[24];
    const float* bl3    = (const float*)d_in[25];
    const float* Wfc3   = (const float*)d_in[26];
    const float* bfc3   = (const float*)d_in[27];
    const float* Wfc4   = (const float*)d_in[28];
    const float* bfc4   = (const float*)d_in[29];
    const float* Wfc5   = (const float*)d_in[30];
    const float* bfc5   = (const float*)d_in[31];
    const float* Wc     = (const float*)d_in[32];
    const float* Wp     = (const float*)d_in[33];
    const float* bpre   = (const float*)d_in[34];

    float* W = (float*)d_ws;
    float* T       = W;  W += 100*NT*128;    // 3,840,000
    float* att     = W;  W += ROWS*128;
    float* satt    = W;  W += ROWS*128;
    float* xemb    = W;  W += ROWS*128;
    float* shiftx  = W;  W += ROWS*128;
    float* fh0     = W;  W += ROWS*128;
    float* fh1     = W;  W += ROWS*128;
    float* wT_in   = W;  W += 512*128;
    float* wT_fg   = W;  W += 512*128;
    float* whhT_in = W;  W += 512*128;
    float* whhT_fg = W;  W += 512*128;
    float* h_in    = W;  W += ROWS*128;
    float* h_fg    = W;  W += ROWS*128;

    hipLaunchKernelGGL(k_stage1, dim3(NB_TR + NB_TP + NB_AT), dim3(256), 0, stream,
        wih_in, wih_fg, whh_in, whh_fg, wT_in, wT_fg, whhT_in, whhT_fg,
        Es, Wc, Wp, T,
        q, c, sq, sc, Eq, att, satt);

    hipLaunchKernelGGL(k_stage2, dim3(NB_PJ + NB_FH), dim3(256), 0, stream,
        q, r, sq, Eq, Er, att, satt, Wl2, bl2, Wl3, bl3, xemb, shiftx,
        c, rg, pc, ac, sc, srg, spc, sac, T, bpre, fh0, fh1);

    hipLaunchKernelGGL(k_lstm, dim3(100, 2), dim3(512), 0, stream,
        xemb, fh0, wT_in, wT_fg, whhT_in, whhT_fg,
        bih_in, bhh_in, bih_fg, bhh_fg, h_in, h_fg);

    hipLaunchKernelGGL(k_final, dim3(400), dim3(256), 0, stream,
        shiftx, h_in, fh1, h_fg, Wfc4, bfc4, Wfc5, bfc5, Wfc3, bfc3, (float*)d_out);
}